// Round 1
// baseline (1336.918 us; speedup 1.0000x reference)
//
#include <hip/hip_runtime.h>

#define N_PTS 32768
#define M_PTS 8192      // N / STRIDE
#define C_IN  64
#define C_OUT 128
#define KNN   16
#define GDIM  67        // 3 + C_IN
#define BN_EPS 1e-5f

// workspace offsets (bytes)
#define OFF_FPS   0u          // int[M_PTS]
#define OFF_POS   32768u      // int[N_PTS]
#define OFF_META  163840u     // int[8]: [0]=nuniq [1]=cycStart [2]=cycLen
#define OFF_PP    163904u     // float[N_PTS]
#define OFF_KNN   294976u     // int[M_PTS*KNN] (only first nuniq*KNN used)
#define OFF_PART  819264u     // float[2048*256]
#define OFF_SCALE 2916416u    // float[C_OUT]
#define OFF_SHIFT 2916928u    // float[C_OUT]

// ---------------- pp = ||p||^2 ----------------
__global__ void pp_kernel(const float* __restrict__ p, float* __restrict__ pp) {
    int i = blockIdx.x * blockDim.x + threadIdx.x;
    if (i < N_PTS) {
        float px = p[3*i], py = p[3*i+1], pz = p[3*i+2];
        pp[i] = px*px + py*py + pz*pz;
    }
}

// ---------------- FPS chain (argmax to LAST point), cycle-detected ----------------
__global__ void __launch_bounds__(1024) fps_kernel(const float* __restrict__ p,
                                                   int* __restrict__ fps,
                                                   int* __restrict__ pos,
                                                   int* __restrict__ meta,
                                                   float* __restrict__ newp) {
    __shared__ float sd[1024];
    __shared__ int   si[1024];
    __shared__ int s_last, s_done, s_cs;
    const int tid = threadIdx.x;

    for (int i = tid; i < N_PTS; i += 1024) pos[i] = -1;
    if (tid == 0) { fps[0] = 0; pos[0] = 0; s_last = 0; s_done = 0; s_cs = 0; }
    __syncthreads();

    int t = 1;
    while (t < M_PTS) {
        const int last = s_last;
        const float qx = p[3*last], qy = p[3*last+1], qz = p[3*last+2];
        float bd = -1.0f; int bi = 0;
        for (int i = tid; i < N_PTS; i += 1024) {
            // match numpy: ((dx^2 + dy^2) + dz^2), no FMA contraction
            float dx = __fsub_rn(p[3*i],   qx);
            float dy = __fsub_rn(p[3*i+1], qy);
            float dz = __fsub_rn(p[3*i+2], qz);
            float d  = __fadd_rn(__fadd_rn(__fmul_rn(dx,dx), __fmul_rn(dy,dy)),
                                 __fmul_rn(dz,dz));
            if (d > bd) { bd = d; bi = i; }   // strict > keeps first (smallest i) per thread
        }
        sd[tid] = bd; si[tid] = bi;
        __syncthreads();
        for (int s = 512; s > 0; s >>= 1) {
            if (tid < s) {
                float od = sd[tid+s]; int oi = si[tid+s];
                if (od > sd[tid] || (od == sd[tid] && oi < si[tid])) {
                    sd[tid] = od; si[tid] = oi;
                }
            }
            __syncthreads();
        }
        if (tid == 0) {
            int nxt = si[0];
            if (pos[nxt] >= 0) { s_cs = pos[nxt]; s_done = 1; }
            else { pos[nxt] = t; fps[t] = nxt; s_last = nxt; }
        }
        __syncthreads();
        if (s_done) break;
        ++t;
    }

    if (tid == 0) {
        if (s_done) { meta[0] = t; meta[1] = s_cs; meta[2] = t - s_cs; }
        else        { meta[0] = M_PTS; meta[1] = 0; meta[2] = 1; }
    }
    __syncthreads();
    if (s_done) {
        const int s = s_cs, L = t - s_cs;
        for (int u = t + tid; u < M_PTS; u += 1024)
            fps[u] = fps[s + (u - s) % L];
    }
    __syncthreads();
    for (int e = tid; e < M_PTS; e += 1024) {
        int id = fps[e];
        newp[3*e]   = p[3*id];
        newp[3*e+1] = p[3*id+1];
        newp[3*e+2] = p[3*id+2];
    }
}

// ---------------- exact kNN for the unique centers only ----------------
__global__ void __launch_bounds__(64) knn_kernel(const float* __restrict__ p,
                                                 const float* __restrict__ pp,
                                                 const int* __restrict__ fps,
                                                 const int* __restrict__ meta,
                                                 int* __restrict__ knn) {
    const int b = blockIdx.x;
    if (b >= meta[0]) return;
    const int lane = threadIdx.x;
    const int cpt = fps[b];
    const float qx = p[3*cpt], qy = p[3*cpt+1], qz = p[3*cpt+2];

    float bd[KNN]; int bi[KNN];
#pragma unroll
    for (int j = 0; j < KNN; ++j) { bd[j] = 3.4e38f; bi[j] = 0x7fffffff; }

    for (int i = lane; i < N_PTS; i += 64) {
        float d = fmaf(-2.0f*qx, p[3*i],   pp[i]);
        d       = fmaf(-2.0f*qy, p[3*i+1], d);
        d       = fmaf(-2.0f*qz, p[3*i+2], d);
        if (d < bd[KNN-1]) {
            bd[KNN-1] = d; bi[KNN-1] = i;
#pragma unroll
            for (int j = KNN-1; j > 0; --j) {
                bool sw = (bd[j] < bd[j-1]) || (bd[j] == bd[j-1] && bi[j] < bi[j-1]);
                if (sw) {
                    float td = bd[j]; bd[j] = bd[j-1]; bd[j-1] = td;
                    int   ti = bi[j]; bi[j] = bi[j-1]; bi[j-1] = ti;
                }
            }
        }
    }

    __shared__ float sdl[64*KNN];
    __shared__ int   sil[64*KNN];
#pragma unroll
    for (int j = 0; j < KNN; ++j) { sdl[lane*KNN+j] = bd[j]; sil[lane*KNN+j] = bi[j]; }
    __syncthreads();

    int head = 0;
    int out_idx = 0;
    for (int r = 0; r < KNN; ++r) {
        float v  = (head < KNN) ? sdl[lane*KNN+head] : 3.4e38f;
        int   id = (head < KNN) ? sil[lane*KNN+head] : 0x7fffffff;
        float bv = v; int bid = id; int bl = lane;
#pragma unroll
        for (int off = 32; off > 0; off >>= 1) {
            float ov = __shfl_xor(bv, off);
            int  oid = __shfl_xor(bid, off);
            int   ol = __shfl_xor(bl, off);
            if (ov < bv || (ov == bv && oid < bid)) { bv = ov; bid = oid; bl = ol; }
        }
        if (lane == r)  out_idx = bid;
        if (lane == bl) ++head;
    }
    if (lane < KNN) knn[b*KNN + lane] = out_idx;
}

// ---------------- pass 1: per-channel sum / sumsq of h (recompute, no h storage) ----
__global__ void __launch_bounds__(128) stats_kernel(const float* __restrict__ p,
                                                    const float* __restrict__ x,
                                                    const float* __restrict__ W,
                                                    const int* __restrict__ knn,
                                                    const int* __restrict__ meta,
                                                    float* __restrict__ part) {
    __shared__ float g[GDIM];
    const int t = threadIdx.x;
    const int nun = meta[0], cs = meta[1], cl = meta[2];
    float s = 0.f, q = 0.f;
    const int r0 = blockIdx.x * 64;
    for (int j = 0; j < 64; ++j) {
        const int r = r0 + j;
        const int m = r >> 4;
        const int slot = (m < nun) ? m : cs + (m - cs) % cl;
        const int pt = knn[slot*KNN + (r & 15)];
        if (t < 3)         g[t] = p[3*pt + t];
        else if (t < GDIM) g[t] = x[(pt << 6) + t - 3];
        __syncthreads();
        float acc = 0.f;
#pragma unroll
        for (int c = 0; c < GDIM; ++c) acc = fmaf(g[c], W[c*C_OUT + t], acc);
        s += acc;
        q = fmaf(acc, acc, q);
        __syncthreads();
    }
    part[blockIdx.x*256 + t]       = s;
    part[blockIdx.x*256 + 128 + t] = q;
}

// ---------------- finalize BN: scale/shift per channel ----------------
__global__ void __launch_bounds__(128) bnfin_kernel(const float* __restrict__ part,
                                                    const float* __restrict__ gamma,
                                                    const float* __restrict__ beta,
                                                    float* __restrict__ scale,
                                                    float* __restrict__ shift) {
    const int t = threadIdx.x;
    float s = 0.f, q = 0.f;
    for (int b = 0; b < 2048; ++b) {
        s += part[b*256 + t];
        q += part[b*256 + 128 + t];
    }
    const float inv = 1.0f / (float)(M_PTS * KNN);
    const float mean = s * inv;
    const float var  = q * inv - mean*mean;
    const float sc   = gamma[t] * rsqrtf(var + BN_EPS);
    scale[t] = sc;
    shift[t] = fmaf(-mean, sc, beta[t]);
}

// ---------------- pass 2: recompute h, normalize+ReLU, maxpool over K -------------
__global__ void __launch_bounds__(128) out_kernel(const float* __restrict__ p,
                                                  const float* __restrict__ x,
                                                  const float* __restrict__ W,
                                                  const int* __restrict__ knn,
                                                  const int* __restrict__ meta,
                                                  const float* __restrict__ scale,
                                                  const float* __restrict__ shift,
                                                  float* __restrict__ xout) {
    __shared__ float g[GDIM];
    const int t = threadIdx.x;
    const int m = blockIdx.x;
    const int nun = meta[0], cs = meta[1], cl = meta[2];
    const int slot = (m < nun) ? m : cs + (m - cs) % cl;
    const float sc = scale[t], sh = shift[t];
    float mx = 0.f;   // max_k relu(y_k) == max(0, max_k y_k)
    for (int k = 0; k < KNN; ++k) {
        const int pt = knn[slot*KNN + k];
        if (t < 3)         g[t] = p[3*pt + t];
        else if (t < GDIM) g[t] = x[(pt << 6) + t - 3];
        __syncthreads();
        float acc = 0.f;
#pragma unroll
        for (int c = 0; c < GDIM; ++c) acc = fmaf(g[c], W[c*C_OUT + t], acc);
        mx = fmaxf(mx, fmaf(acc, sc, sh));
        __syncthreads();
    }
    xout[m*C_OUT + t] = mx;
}

extern "C" void kernel_launch(void* const* d_in, const int* in_sizes, int n_in,
                              void* d_out, int out_size, void* d_ws, size_t ws_size,
                              hipStream_t stream) {
    (void)in_sizes; (void)n_in; (void)out_size; (void)ws_size;
    const float* p     = (const float*)d_in[0];
    const float* x     = (const float*)d_in[1];
    // d_in[2] = o (unused)
    const float* W     = (const float*)d_in[3];
    const float* gamma = (const float*)d_in[4];
    const float* beta  = (const float*)d_in[5];

    float* out  = (float*)d_out;
    float* newp = out;               // [M_PTS, 3]
    float* xout = out + M_PTS * 3;   // [M_PTS, C_OUT]

    char* ws = (char*)d_ws;
    int*   fps   = (int*)  (ws + OFF_FPS);
    int*   pos   = (int*)  (ws + OFF_POS);
    int*   meta  = (int*)  (ws + OFF_META);
    float* pp    = (float*)(ws + OFF_PP);
    int*   knn   = (int*)  (ws + OFF_KNN);
    float* part  = (float*)(ws + OFF_PART);
    float* scale = (float*)(ws + OFF_SCALE);
    float* shift = (float*)(ws + OFF_SHIFT);

    pp_kernel   <<<(N_PTS + 255)/256, 256, 0, stream>>>(p, pp);
    fps_kernel  <<<1, 1024, 0, stream>>>(p, fps, pos, meta, newp);
    knn_kernel  <<<M_PTS, 64, 0, stream>>>(p, pp, fps, meta, knn);
    stats_kernel<<<2048, 128, 0, stream>>>(p, x, W, knn, meta, part);
    bnfin_kernel<<<1, 128, 0, stream>>>(part, gamma, beta, scale, shift);
    out_kernel  <<<M_PTS, 128, 0, stream>>>(p, x, W, knn, meta, scale, shift, xout);
}

// Round 2
// 339.303 us; speedup vs baseline: 3.9402x; 3.9402x over previous
//
#include <hip/hip_runtime.h>

#define N_PTS 32768
#define M_PTS 8192      // N / STRIDE
#define C_IN  64
#define C_OUT 128
#define KNN   16
#define GDIM  67        // 3 + C_IN
#define BN_EPS 1e-5f

// workspace offsets (bytes)
#define OFF_FPS   0u          // int[M_PTS]
#define OFF_POS   32768u      // int[N_PTS]
#define OFF_META  163840u     // int[8]: [0]=nuniq [1]=cycStart [2]=cycLen
#define OFF_PP    163904u     // float[N_PTS]
#define OFF_KNN   294976u     // int[M_PTS*KNN] (only first nuniq*KNN used)
#define OFF_PART  819264u     // float[2048*256]
#define OFF_SCALE 2916416u    // float[C_OUT]
#define OFF_SHIFT 2916928u    // float[C_OUT]

// ---------------- pp = ||p||^2 ----------------
__global__ void pp_kernel(const float* __restrict__ p, float* __restrict__ pp) {
    int i = blockIdx.x * blockDim.x + threadIdx.x;
    if (i < N_PTS) {
        float px = p[3*i], py = p[3*i+1], pz = p[3*i+2];
        pp[i] = px*px + py*py + pz*pz;
    }
}

// ---------------- FPS chain (argmax to LAST point), cycle-detected ----------------
__global__ void __launch_bounds__(1024) fps_kernel(const float* __restrict__ p,
                                                   int* __restrict__ fps,
                                                   int* __restrict__ pos,
                                                   int* __restrict__ meta,
                                                   float* __restrict__ newp) {
    __shared__ float sd[1024];
    __shared__ int   si[1024];
    __shared__ int s_last, s_done, s_cs;
    const int tid = threadIdx.x;

    for (int i = tid; i < N_PTS; i += 1024) pos[i] = -1;
    if (tid == 0) { fps[0] = 0; pos[0] = 0; s_last = 0; s_done = 0; s_cs = 0; }
    __syncthreads();

    int t = 1;
    while (t < M_PTS) {
        const int last = s_last;
        const float qx = p[3*last], qy = p[3*last+1], qz = p[3*last+2];
        float bd = -1.0f; int bi = 0;
        for (int i = tid; i < N_PTS; i += 1024) {
            // match numpy: ((dx^2 + dy^2) + dz^2), no FMA contraction
            float dx = __fsub_rn(p[3*i],   qx);
            float dy = __fsub_rn(p[3*i+1], qy);
            float dz = __fsub_rn(p[3*i+2], qz);
            float d  = __fadd_rn(__fadd_rn(__fmul_rn(dx,dx), __fmul_rn(dy,dy)),
                                 __fmul_rn(dz,dz));
            if (d > bd) { bd = d; bi = i; }   // strict > keeps first (smallest i) per thread
        }
        sd[tid] = bd; si[tid] = bi;
        __syncthreads();
        for (int s = 512; s > 0; s >>= 1) {
            if (tid < s) {
                float od = sd[tid+s]; int oi = si[tid+s];
                if (od > sd[tid] || (od == sd[tid] && oi < si[tid])) {
                    sd[tid] = od; si[tid] = oi;
                }
            }
            __syncthreads();
        }
        if (tid == 0) {
            int nxt = si[0];
            if (pos[nxt] >= 0) { s_cs = pos[nxt]; s_done = 1; }
            else { pos[nxt] = t; fps[t] = nxt; s_last = nxt; }
        }
        __syncthreads();
        if (s_done) break;
        ++t;
    }

    if (tid == 0) {
        if (s_done) { meta[0] = t; meta[1] = s_cs; meta[2] = t - s_cs; }
        else        { meta[0] = M_PTS; meta[1] = 0; meta[2] = 1; }
    }
    __syncthreads();
    if (s_done) {
        const int s = s_cs, L = t - s_cs;
        for (int u = t + tid; u < M_PTS; u += 1024)
            fps[u] = fps[s + (u - s) % L];
    }
    __syncthreads();
    for (int e = tid; e < M_PTS; e += 1024) {
        int id = fps[e];
        newp[3*e]   = p[3*id];
        newp[3*e+1] = p[3*id+1];
        newp[3*e+2] = p[3*id+2];
    }
}

// ---------------- exact kNN for the unique centers, 1024 threads/center ----------
// Per-thread register-resident sorted top-16 over 32 points (static indices only),
// then 16-round tournament merge: wave shfl lex-min -> per-wave winners in LDS ->
// wave-0 reduce -> winning thread shifts its list down (head stays at index 0).
__global__ void __launch_bounds__(1024) knn_kernel(const float* __restrict__ p,
                                                   const float* __restrict__ pp,
                                                   const int* __restrict__ fps,
                                                   const int* __restrict__ meta,
                                                   int* __restrict__ knn) {
    const int b = blockIdx.x;
    if (b >= meta[0]) return;
    const int tid  = threadIdx.x;
    const int lane = tid & 63;
    const int wid  = tid >> 6;          // 16 waves

    const int cpt = fps[b];
    const float qx = p[3*cpt], qy = p[3*cpt+1], qz = p[3*cpt+2];

    float bd[KNN]; int bi[KNN];
#pragma unroll
    for (int j = 0; j < KNN; ++j) { bd[j] = 3.4e38f; bi[j] = 0x7fffffff; }

    // each thread scans 32 points: i = tid + 1024*j  (coalesced across lanes)
#pragma unroll 4
    for (int j = 0; j < N_PTS / 1024; ++j) {
        const int i = tid + (j << 10);
        float d = fmaf(-2.0f*qx, p[3*i],   pp[i]);
        d       = fmaf(-2.0f*qy, p[3*i+1], d);
        d       = fmaf(-2.0f*qz, p[3*i+2], d);
        if (d < bd[KNN-1]) {
            bd[KNN-1] = d; bi[KNN-1] = i;
#pragma unroll
            for (int k = KNN-1; k > 0; --k) {
                bool sw = (bd[k] < bd[k-1]) || (bd[k] == bd[k-1] && bi[k] < bi[k-1]);
                if (sw) {
                    float td = bd[k]; bd[k] = bd[k-1]; bd[k-1] = td;
                    int   ti = bi[k]; bi[k] = bi[k-1]; bi[k-1] = ti;
                }
            }
        }
    }

    __shared__ float wv_d[16];
    __shared__ int   wv_i[16];
    __shared__ int   wv_t[16];
    __shared__ float gw_d;
    __shared__ int   gw_i;
    __shared__ int   gw_t;

    for (int r = 0; r < KNN; ++r) {
        // wave-level lex-min over (d, idx); carry owner tid
        float bv = bd[0]; int bid = bi[0]; int bt = tid;
#pragma unroll
        for (int off = 32; off > 0; off >>= 1) {
            float ov = __shfl_xor(bv, off);
            int  oid = __shfl_xor(bid, off);
            int  ot  = __shfl_xor(bt, off);
            if (ov < bv || (ov == bv && oid < bid)) { bv = ov; bid = oid; bt = ot; }
        }
        if (lane == 0) { wv_d[wid] = bv; wv_i[wid] = bid; wv_t[wid] = bt; }
        __syncthreads();
        // wave 0 reduces the 16 per-wave winners
        if (wid == 0) {
            float rv = (lane < 16) ? wv_d[lane] : 3.4e38f;
            int   ri = (lane < 16) ? wv_i[lane] : 0x7fffffff;
            int   rt = (lane < 16) ? wv_t[lane] : 0;
#pragma unroll
            for (int off = 8; off > 0; off >>= 1) {
                float ov = __shfl_xor(rv, off);
                int  oid = __shfl_xor(ri, off);
                int  ot  = __shfl_xor(rt, off);
                if (ov < rv || (ov == rv && oid < ri)) { rv = ov; ri = oid; rt = ot; }
            }
            if (lane == 0) { gw_d = rv; gw_i = ri; gw_t = rt; }
        }
        __syncthreads();
        const int win_i = gw_i;
        const int win_t = gw_t;
        if (tid == 0) knn[b*KNN + r] = win_i;
        if (tid == win_t) {
            // consume head: shift register list down (all static indices)
#pragma unroll
            for (int k = 0; k < KNN-1; ++k) { bd[k] = bd[k+1]; bi[k] = bi[k+1]; }
            bd[KNN-1] = 3.4e38f; bi[KNN-1] = 0x7fffffff;
        }
        __syncthreads();
    }
}

// ---------------- pass 1: per-channel sum / sumsq of h (recompute, no h storage) ----
__global__ void __launch_bounds__(128) stats_kernel(const float* __restrict__ p,
                                                    const float* __restrict__ x,
                                                    const float* __restrict__ W,
                                                    const int* __restrict__ knn,
                                                    const int* __restrict__ meta,
                                                    float* __restrict__ part) {
    __shared__ float g[GDIM];
    const int t = threadIdx.x;
    const int nun = meta[0], cs = meta[1], cl = meta[2];
    float s = 0.f, q = 0.f;
    const int r0 = blockIdx.x * 64;
    for (int j = 0; j < 64; ++j) {
        const int r = r0 + j;
        const int m = r >> 4;
        const int slot = (m < nun) ? m : cs + (m - cs) % cl;
        const int pt = knn[slot*KNN + (r & 15)];
        if (t < 3)         g[t] = p[3*pt + t];
        else if (t < GDIM) g[t] = x[(pt << 6) + t - 3];
        __syncthreads();
        float acc = 0.f;
#pragma unroll
        for (int c = 0; c < GDIM; ++c) acc = fmaf(g[c], W[c*C_OUT + t], acc);
        s += acc;
        q = fmaf(acc, acc, q);
        __syncthreads();
    }
    part[blockIdx.x*256 + t]       = s;
    part[blockIdx.x*256 + 128 + t] = q;
}

// ---------------- finalize BN: scale/shift per channel ----------------
__global__ void __launch_bounds__(128) bnfin_kernel(const float* __restrict__ part,
                                                    const float* __restrict__ gamma,
                                                    const float* __restrict__ beta,
                                                    float* __restrict__ scale,
                                                    float* __restrict__ shift) {
    const int t = threadIdx.x;
    float s = 0.f, q = 0.f;
    for (int b = 0; b < 2048; ++b) {
        s += part[b*256 + t];
        q += part[b*256 + 128 + t];
    }
    const float inv = 1.0f / (float)(M_PTS * KNN);
    const float mean = s * inv;
    const float var  = q * inv - mean*mean;
    const float sc   = gamma[t] * rsqrtf(var + BN_EPS);
    scale[t] = sc;
    shift[t] = fmaf(-mean, sc, beta[t]);
}

// ---------------- pass 2: recompute h, normalize+ReLU, maxpool over K -------------
__global__ void __launch_bounds__(128) out_kernel(const float* __restrict__ p,
                                                  const float* __restrict__ x,
                                                  const float* __restrict__ W,
                                                  const int* __restrict__ knn,
                                                  const int* __restrict__ meta,
                                                  const float* __restrict__ scale,
                                                  const float* __restrict__ shift,
                                                  float* __restrict__ xout) {
    __shared__ float g[GDIM];
    const int t = threadIdx.x;
    const int m = blockIdx.x;
    const int nun = meta[0], cs = meta[1], cl = meta[2];
    const int slot = (m < nun) ? m : cs + (m - cs) % cl;
    const float sc = scale[t], sh = shift[t];
    float mx = 0.f;   // max_k relu(y_k) == max(0, max_k y_k)
    for (int k = 0; k < KNN; ++k) {
        const int pt = knn[slot*KNN + k];
        if (t < 3)         g[t] = p[3*pt + t];
        else if (t < GDIM) g[t] = x[(pt << 6) + t - 3];
        __syncthreads();
        float acc = 0.f;
#pragma unroll
        for (int c = 0; c < GDIM; ++c) acc = fmaf(g[c], W[c*C_OUT + t], acc);
        mx = fmaxf(mx, fmaf(acc, sc, sh));
        __syncthreads();
    }
    xout[m*C_OUT + t] = mx;
}

extern "C" void kernel_launch(void* const* d_in, const int* in_sizes, int n_in,
                              void* d_out, int out_size, void* d_ws, size_t ws_size,
                              hipStream_t stream) {
    (void)in_sizes; (void)n_in; (void)out_size; (void)ws_size;
    const float* p     = (const float*)d_in[0];
    const float* x     = (const float*)d_in[1];
    // d_in[2] = o (unused)
    const float* W     = (const float*)d_in[3];
    const float* gamma = (const float*)d_in[4];
    const float* beta  = (const float*)d_in[5];

    float* out  = (float*)d_out;
    float* newp = out;               // [M_PTS, 3]
    float* xout = out + M_PTS * 3;   // [M_PTS, C_OUT]

    char* ws = (char*)d_ws;
    int*   fps   = (int*)  (ws + OFF_FPS);
    int*   pos   = (int*)  (ws + OFF_POS);
    int*   meta  = (int*)  (ws + OFF_META);
    float* pp    = (float*)(ws + OFF_PP);
    int*   knn   = (int*)  (ws + OFF_KNN);
    float* part  = (float*)(ws + OFF_PART);
    float* scale = (float*)(ws + OFF_SCALE);
    float* shift = (float*)(ws + OFF_SHIFT);

    pp_kernel   <<<(N_PTS + 255)/256, 256, 0, stream>>>(p, pp);
    fps_kernel  <<<1, 1024, 0, stream>>>(p, fps, pos, meta, newp);
    knn_kernel  <<<M_PTS, 1024, 0, stream>>>(p, pp, fps, meta, knn);
    stats_kernel<<<2048, 128, 0, stream>>>(p, x, W, knn, meta, part);
    bnfin_kernel<<<1, 128, 0, stream>>>(part, gamma, beta, scale, shift);
    out_kernel  <<<M_PTS, 128, 0, stream>>>(p, x, W, knn, meta, scale, shift, xout);
}

// Round 3
// 181.390 us; speedup vs baseline: 7.3704x; 1.8706x over previous
//
#include <hip/hip_runtime.h>

#define N_PTS 32768
#define M_PTS 8192      // N / STRIDE
#define C_IN  64
#define C_OUT 128
#define KNN   16
#define GDIM  67        // 3 + C_IN
#define BN_EPS 1e-5f
#define SBLK  64        // blocks for ustats/uout grid-stride

// workspace offsets (bytes)
#define OFF_FPS   0u          // int[M_PTS]
#define OFF_POS   32768u      // int[N_PTS]
#define OFF_META  163840u     // int[8]: [0]=nuniq [1]=cycStart [2]=cycLen
#define OFF_PP    163904u     // float[N_PTS]
#define OFF_KNN   294976u     // int[M_PTS*KNN] (only first nuniq*KNN used)
#define OFF_PART  819264u     // float[SBLK*256]
#define OFF_SCALE 884800u     // float[C_OUT]
#define OFF_SHIFT 885312u     // float[C_OUT]

// multiplicity of unique slot s in the length-M periodic index sequence
__device__ __forceinline__ int slot_count(int s, int nun, int cs, int cl, int M) {
    if (s < cs) return 1;                 // pre-cycle slot: occurs once
    const int E = M - nun;                // extended (periodic) occurrences
    const int base = E / cl, rem = E % cl;
    const int start = (nun - cs) % cl;    // residue of first extended index
    int off = (s - cs) - start; if (off < 0) off += cl;
    return 1 + base + (off < rem ? 1 : 0);
}

// ---------------- pp = ||p||^2 ----------------
__global__ void pp_kernel(const float* __restrict__ p, float* __restrict__ pp) {
    int i = blockIdx.x * blockDim.x + threadIdx.x;
    if (i < N_PTS) {
        float px = p[3*i], py = p[3*i+1], pz = p[3*i+2];
        pp[i] = px*px + py*py + pz*pz;
    }
}

// ---------------- FPS chain (argmax to LAST point), cycle-detected ----------------
__global__ void __launch_bounds__(1024) fps_kernel(const float* __restrict__ p,
                                                   int* __restrict__ fps,
                                                   int* __restrict__ pos,
                                                   int* __restrict__ meta,
                                                   float* __restrict__ newp) {
    __shared__ float sd[1024];
    __shared__ int   si[1024];
    __shared__ int s_last, s_done, s_cs;
    const int tid = threadIdx.x;

    for (int i = tid; i < N_PTS; i += 1024) pos[i] = -1;
    if (tid == 0) { fps[0] = 0; pos[0] = 0; s_last = 0; s_done = 0; s_cs = 0; }
    __syncthreads();

    int t = 1;
    while (t < M_PTS) {
        const int last = s_last;
        const float qx = p[3*last], qy = p[3*last+1], qz = p[3*last+2];
        float bd = -1.0f; int bi = 0;
        for (int i = tid; i < N_PTS; i += 1024) {
            // match numpy: ((dx^2 + dy^2) + dz^2), no FMA contraction
            float dx = __fsub_rn(p[3*i],   qx);
            float dy = __fsub_rn(p[3*i+1], qy);
            float dz = __fsub_rn(p[3*i+2], qz);
            float d  = __fadd_rn(__fadd_rn(__fmul_rn(dx,dx), __fmul_rn(dy,dy)),
                                 __fmul_rn(dz,dz));
            if (d > bd) { bd = d; bi = i; }   // strict > keeps first (smallest i) per thread
        }
        sd[tid] = bd; si[tid] = bi;
        __syncthreads();
        for (int s = 512; s > 0; s >>= 1) {
            if (tid < s) {
                float od = sd[tid+s]; int oi = si[tid+s];
                if (od > sd[tid] || (od == sd[tid] && oi < si[tid])) {
                    sd[tid] = od; si[tid] = oi;
                }
            }
            __syncthreads();
        }
        if (tid == 0) {
            int nxt = si[0];
            if (pos[nxt] >= 0) { s_cs = pos[nxt]; s_done = 1; }
            else { pos[nxt] = t; fps[t] = nxt; s_last = nxt; }
        }
        __syncthreads();
        if (s_done) break;
        ++t;
    }

    if (tid == 0) {
        if (s_done) { meta[0] = t; meta[1] = s_cs; meta[2] = t - s_cs; }
        else        { meta[0] = M_PTS; meta[1] = 0; meta[2] = 1; }
    }
    __syncthreads();
    if (s_done) {
        const int s = s_cs, L = t - s_cs;
        for (int u = t + tid; u < M_PTS; u += 1024)
            fps[u] = fps[s + (u - s) % L];
    }
    __syncthreads();
    for (int e = tid; e < M_PTS; e += 1024) {
        int id = fps[e];
        newp[3*e]   = p[3*id];
        newp[3*e+1] = p[3*id+1];
        newp[3*e+2] = p[3*id+2];
    }
}

// ---------------- exact kNN, unique centers only, small fixed grid ----------------
__global__ void __launch_bounds__(1024) knn_kernel(const float* __restrict__ p,
                                                   const float* __restrict__ pp,
                                                   const int* __restrict__ fps,
                                                   const int* __restrict__ meta,
                                                   int* __restrict__ knn) {
    const int tid  = threadIdx.x;
    const int lane = tid & 63;
    const int wid  = tid >> 6;          // 16 waves
    const int nun  = meta[0];

    __shared__ float wv_d[16];
    __shared__ int   wv_i[16];
    __shared__ int   wv_t[16];
    __shared__ int   gw_i;
    __shared__ int   gw_t;

    for (int b = blockIdx.x; b < nun; b += gridDim.x) {
        const int cpt = fps[b];
        const float qx = p[3*cpt], qy = p[3*cpt+1], qz = p[3*cpt+2];

        float bd[KNN]; int bi[KNN];
#pragma unroll
        for (int j = 0; j < KNN; ++j) { bd[j] = 3.4e38f; bi[j] = 0x7fffffff; }

        // each thread scans 32 points: i = tid + 1024*j (coalesced across lanes)
#pragma unroll 4
        for (int j = 0; j < N_PTS / 1024; ++j) {
            const int i = tid + (j << 10);
            float d = fmaf(-2.0f*qx, p[3*i],   pp[i]);
            d       = fmaf(-2.0f*qy, p[3*i+1], d);
            d       = fmaf(-2.0f*qz, p[3*i+2], d);
            if (d < bd[KNN-1]) {
                bd[KNN-1] = d; bi[KNN-1] = i;
#pragma unroll
                for (int k = KNN-1; k > 0; --k) {
                    bool sw = (bd[k] < bd[k-1]) || (bd[k] == bd[k-1] && bi[k] < bi[k-1]);
                    if (sw) {
                        float td = bd[k]; bd[k] = bd[k-1]; bd[k-1] = td;
                        int   ti = bi[k]; bi[k] = bi[k-1]; bi[k-1] = ti;
                    }
                }
            }
        }

        for (int r = 0; r < KNN; ++r) {
            // wave-level lex-min over (d, idx); carry owner tid
            float bv = bd[0]; int bid = bi[0]; int bt = tid;
#pragma unroll
            for (int off = 32; off > 0; off >>= 1) {
                float ov = __shfl_xor(bv, off);
                int  oid = __shfl_xor(bid, off);
                int  ot  = __shfl_xor(bt, off);
                if (ov < bv || (ov == bv && oid < bid)) { bv = ov; bid = oid; bt = ot; }
            }
            if (lane == 0) { wv_d[wid] = bv; wv_i[wid] = bid; wv_t[wid] = bt; }
            __syncthreads();
            if (wid == 0) {
                float rv = (lane < 16) ? wv_d[lane] : 3.4e38f;
                int   ri = (lane < 16) ? wv_i[lane] : 0x7fffffff;
                int   rt = (lane < 16) ? wv_t[lane] : 0;
#pragma unroll
                for (int off = 8; off > 0; off >>= 1) {
                    float ov = __shfl_xor(rv, off);
                    int  oid = __shfl_xor(ri, off);
                    int  ot  = __shfl_xor(rt, off);
                    if (ov < rv || (ov == rv && oid < ri)) { rv = ov; ri = oid; rt = ot; }
                }
                if (lane == 0) { gw_i = ri; gw_t = rt; }
            }
            __syncthreads();
            const int win_i = gw_i;
            const int win_t = gw_t;
            if (tid == 0) knn[b*KNN + r] = win_i;
            if (tid == win_t) {
#pragma unroll
                for (int k = 0; k < KNN-1; ++k) { bd[k] = bd[k+1]; bi[k] = bi[k+1]; }
                bd[KNN-1] = 3.4e38f; bi[KNN-1] = 0x7fffffff;
            }
            __syncthreads();
        }
    }
}

// ---- unique-slot stats: weighted per-channel sum/sumsq of h over nuniq slots ----
__global__ void __launch_bounds__(128) ustats_kernel(const float* __restrict__ p,
                                                     const float* __restrict__ x,
                                                     const float* __restrict__ W,
                                                     const int* __restrict__ knn,
                                                     const int* __restrict__ meta,
                                                     float* __restrict__ part) {
    __shared__ float g[GDIM];
    const int t = threadIdx.x;
    const int nun = meta[0], cs = meta[1], cl = meta[2];
    float s_sum = 0.f, s_sq = 0.f;
    for (int s = blockIdx.x; s < nun; s += SBLK) {
        float ls = 0.f, lq = 0.f;
        for (int k = 0; k < KNN; ++k) {
            const int pt = knn[s*KNN + k];
            if (t < 3)         g[t] = p[3*pt + t];
            else if (t < GDIM) g[t] = x[(pt << 6) + t - 3];
            __syncthreads();
            float acc = 0.f;
#pragma unroll
            for (int c = 0; c < GDIM; ++c) acc = fmaf(g[c], W[c*C_OUT + t], acc);
            ls += acc;
            lq = fmaf(acc, acc, lq);
            __syncthreads();
        }
        const float cf = (float)slot_count(s, nun, cs, cl, M_PTS);
        s_sum = fmaf(cf, ls, s_sum);
        s_sq  = fmaf(cf, lq, s_sq);
    }
    part[blockIdx.x*256 + t]       = s_sum;
    part[blockIdx.x*256 + 128 + t] = s_sq;
}

// ---------------- finalize BN: scale/shift per channel ----------------
__global__ void __launch_bounds__(128) bnfin_kernel(const float* __restrict__ part,
                                                    const float* __restrict__ gamma,
                                                    const float* __restrict__ beta,
                                                    float* __restrict__ scale,
                                                    float* __restrict__ shift) {
    const int t = threadIdx.x;
    float s = 0.f, q = 0.f;
    for (int b = 0; b < SBLK; ++b) {
        s += part[b*256 + t];
        q += part[b*256 + 128 + t];
    }
    const float inv = 1.0f / (float)(M_PTS * KNN);
    const float mean = s * inv;
    const float var  = q * inv - mean*mean;
    const float sc   = gamma[t] * rsqrtf(var + BN_EPS);
    scale[t] = sc;
    shift[t] = fmaf(-mean, sc, beta[t]);
}

// ---- unique-slot output rows: slot(m)==m for m<nuniq, write directly to xout ----
__global__ void __launch_bounds__(128) uout_kernel(const float* __restrict__ p,
                                                   const float* __restrict__ x,
                                                   const float* __restrict__ W,
                                                   const int* __restrict__ knn,
                                                   const int* __restrict__ meta,
                                                   const float* __restrict__ scale,
                                                   const float* __restrict__ shift,
                                                   float* __restrict__ xout) {
    __shared__ float g[GDIM];
    const int t = threadIdx.x;
    const int nun = meta[0];
    const float sc = scale[t], sh = shift[t];
    for (int s = blockIdx.x; s < nun; s += SBLK) {
        float mx = 0.f;   // max_k relu(y_k) == max(0, max_k y_k)
        for (int k = 0; k < KNN; ++k) {
            const int pt = knn[s*KNN + k];
            if (t < 3)         g[t] = p[3*pt + t];
            else if (t < GDIM) g[t] = x[(pt << 6) + t - 3];
            __syncthreads();
            float acc = 0.f;
#pragma unroll
            for (int c = 0; c < GDIM; ++c) acc = fmaf(g[c], W[c*C_OUT + t], acc);
            mx = fmaxf(mx, fmaf(acc, sc, sh));
            __syncthreads();
        }
        xout[s*C_OUT + t] = mx;
    }
}

// ---- broadcast periodic rows: xout[m] = xout[slot(m)] for m >= nuniq (float4) ----
__global__ void __launch_bounds__(256) bcast_kernel(const int* __restrict__ meta,
                                                    float* __restrict__ xout) {
    const int nun = meta[0], cs = meta[1], cl = meta[2];
    const int idx = blockIdx.x * 256 + threadIdx.x;      // float4 index
    const int m = nun + (idx >> 5);                      // 32 float4 per row
    if (m >= M_PTS) return;
    const int c4 = idx & 31;
    const int sl = cs + (m - cs) % cl;
    float4 v = ((const float4*)xout)[sl*32 + c4];
    ((float4*)xout)[(size_t)m*32 + c4] = v;
}

extern "C" void kernel_launch(void* const* d_in, const int* in_sizes, int n_in,
                              void* d_out, int out_size, void* d_ws, size_t ws_size,
                              hipStream_t stream) {
    (void)in_sizes; (void)n_in; (void)out_size; (void)ws_size;
    const float* p     = (const float*)d_in[0];
    const float* x     = (const float*)d_in[1];
    // d_in[2] = o (unused)
    const float* W     = (const float*)d_in[3];
    const float* gamma = (const float*)d_in[4];
    const float* beta  = (const float*)d_in[5];

    float* out  = (float*)d_out;
    float* newp = out;               // [M_PTS, 3]
    float* xout = out + M_PTS * 3;   // [M_PTS, C_OUT]

    char* ws = (char*)d_ws;
    int*   fps   = (int*)  (ws + OFF_FPS);
    int*   pos   = (int*)  (ws + OFF_POS);
    int*   meta  = (int*)  (ws + OFF_META);
    float* pp    = (float*)(ws + OFF_PP);
    int*   knn   = (int*)  (ws + OFF_KNN);
    float* part  = (float*)(ws + OFF_PART);
    float* scale = (float*)(ws + OFF_SCALE);
    float* shift = (float*)(ws + OFF_SHIFT);

    pp_kernel    <<<(N_PTS + 255)/256, 256, 0, stream>>>(p, pp);
    fps_kernel   <<<1, 1024, 0, stream>>>(p, fps, pos, meta, newp);
    knn_kernel   <<<16, 1024, 0, stream>>>(p, pp, fps, meta, knn);
    ustats_kernel<<<SBLK, 128, 0, stream>>>(p, x, W, knn, meta, part);
    bnfin_kernel <<<1, 128, 0, stream>>>(part, gamma, beta, scale, shift);
    uout_kernel  <<<SBLK, 128, 0, stream>>>(p, x, W, knn, meta, scale, shift, xout);
    bcast_kernel <<<M_PTS*32/256, 256, 0, stream>>>(meta, xout);
}

// Round 4
// 138.405 us; speedup vs baseline: 9.6595x; 1.3106x over previous
//
#include <hip/hip_runtime.h>

#define N_PTS 32768
#define M_PTS 8192      // N / STRIDE
#define C_IN  64
#define C_OUT 128
#define KNN   16
#define GDIM  67        // 3 + C_IN
#define BN_EPS 1e-5f
#define SBLK  64        // blocks for ustats/uout grid-stride

// workspace offsets (bytes)
#define OFF_FPS   0u          // int[M_PTS]
#define OFF_POS   32768u      // int[N_PTS]
#define OFF_META  163840u     // int[8]: [0]=nuniq [1]=cycStart [2]=cycLen
#define OFF_PP    163904u     // float[N_PTS]
#define OFF_KNN   294976u     // int[M_PTS*KNN] (only first nuniq*KNN used)
#define OFF_PART  819264u     // float[SBLK*256]
#define OFF_SCALE 884800u     // float[C_OUT]
#define OFF_SHIFT 885312u     // float[C_OUT]

typedef unsigned int uint32;
typedef unsigned long long uint64;

// multiplicity of unique slot s in the length-M periodic index sequence
__device__ __forceinline__ int slot_count(int s, int nun, int cs, int cl, int M) {
    if (s < cs) return 1;                 // pre-cycle slot: occurs once
    const int E = M - nun;                // extended (periodic) occurrences
    const int base = E / cl, rem = E % cl;
    const int start = (nun - cs) % cl;    // residue of first extended index
    int off = (s - cs) - start; if (off < 0) off += cl;
    return 1 + base + (off < rem ? 1 : 0);
}

// ---------------- pp = ||p||^2 ----------------
__global__ void pp_kernel(const float* __restrict__ p, float* __restrict__ pp) {
    int i = blockIdx.x * blockDim.x + threadIdx.x;
    if (i < N_PTS) {
        float px = p[3*i], py = p[3*i+1], pz = p[3*i+2];
        pp[i] = px*px + py*py + pz*pz;
    }
}

// ---------------- FPS chain (argmax to LAST point), cycle-detected ----------------
// v2: wave-shfl lex-max reduce (2 syncthreads/step instead of 11)
__global__ void __launch_bounds__(1024) fps_kernel(const float* __restrict__ p,
                                                   int* __restrict__ fps,
                                                   int* __restrict__ pos,
                                                   int* __restrict__ meta,
                                                   float* __restrict__ newp) {
    __shared__ float wv_d[16];
    __shared__ int   wv_i[16];
    __shared__ int s_last, s_done, s_cs;
    const int tid  = threadIdx.x;
    const int lane = tid & 63;
    const int wid  = tid >> 6;

    for (int i = tid; i < N_PTS; i += 1024) pos[i] = -1;
    if (tid == 0) { fps[0] = 0; pos[0] = 0; s_last = 0; s_done = 0; s_cs = 0; }
    __syncthreads();

    int t = 1;
    while (t < M_PTS) {
        const int last = s_last;
        const float qx = p[3*last], qy = p[3*last+1], qz = p[3*last+2];
        float bd = -1.0f; int bi = 0;
        for (int i = tid; i < N_PTS; i += 1024) {
            // match numpy: ((dx^2 + dy^2) + dz^2), no FMA contraction
            float dx = __fsub_rn(p[3*i],   qx);
            float dy = __fsub_rn(p[3*i+1], qy);
            float dz = __fsub_rn(p[3*i+2], qz);
            float d  = __fadd_rn(__fadd_rn(__fmul_rn(dx,dx), __fmul_rn(dy,dy)),
                                 __fmul_rn(dz,dz));
            if (d > bd) { bd = d; bi = i; }   // strict > keeps first (smallest i) per thread
        }
        // wave-level lex-max (d, then smaller idx)
#pragma unroll
        for (int off = 32; off > 0; off >>= 1) {
            float od = __shfl_xor(bd, off);
            int   oi = __shfl_xor(bi, off);
            if (od > bd || (od == bd && oi < bi)) { bd = od; bi = oi; }
        }
        if (lane == 0) { wv_d[wid] = bd; wv_i[wid] = bi; }
        __syncthreads();
        if (wid == 0) {
            float rd = (lane < 16) ? wv_d[lane] : -1.0f;
            int   ri = (lane < 16) ? wv_i[lane] : 0x7fffffff;
#pragma unroll
            for (int off = 8; off > 0; off >>= 1) {
                float od = __shfl_xor(rd, off);
                int   oi = __shfl_xor(ri, off);
                if (od > rd || (od == rd && oi < ri)) { rd = od; ri = oi; }
            }
            if (lane == 0) {
                int nxt = ri;
                if (pos[nxt] >= 0) { s_cs = pos[nxt]; s_done = 1; }
                else { pos[nxt] = t; fps[t] = nxt; s_last = nxt; }
            }
        }
        __syncthreads();
        if (s_done) break;
        ++t;
    }

    if (tid == 0) {
        if (s_done) { meta[0] = t; meta[1] = s_cs; meta[2] = t - s_cs; }
        else        { meta[0] = M_PTS; meta[1] = 0; meta[2] = 1; }
    }
    __syncthreads();
    if (s_done) {
        const int s = s_cs, L = t - s_cs;
        for (int u = t + tid; u < M_PTS; u += 1024)
            fps[u] = fps[s + (u - s) % L];
    }
    __syncthreads();
    for (int e = tid; e < M_PTS; e += 1024) {
        int id = fps[e];
        newp[3*e]   = p[3*id];
        newp[3*e+1] = p[3*id+1];
        newp[3*e+2] = p[3*id+2];
    }
}

// ---------------- exact kNN via MSB radix-select (branch-light) ----------------
// Keys: monotone float->uint transform of the same distance values as before.
// 8 passes x 4-bit digits with per-wave padded LDS histograms; then collect
// key<=T candidates and extract 16 lex-min (key,idx) as packed u64.
__global__ void __launch_bounds__(1024) knn_kernel(const float* __restrict__ p,
                                                   const float* __restrict__ pp,
                                                   const int* __restrict__ fps,
                                                   const int* __restrict__ meta,
                                                   int* __restrict__ knn) {
    const int tid  = threadIdx.x;
    const int lane = tid & 63;
    const int wid  = tid >> 6;          // 16 waves
    const int nun  = meta[0];

    __shared__ uint32 hist[16*17];      // per-wave 16 bins, padded stride 17
    __shared__ uint32 s_sel[2];         // [0]=prefix [1]=kth
    __shared__ int    s_cnt;
    __shared__ uint64 list[1024];

    for (int b = blockIdx.x; b < nun; b += gridDim.x) {
        const int cpt = fps[b];
        const float qx = p[3*cpt], qy = p[3*cpt+1], qz = p[3*cpt+2];

        uint32 kj[32];
#pragma unroll
        for (int j = 0; j < 32; ++j) {
            const int i = tid + (j << 10);
            float d = fmaf(-2.0f*qx, p[3*i],   pp[i]);
            d       = fmaf(-2.0f*qy, p[3*i+1], d);
            d       = fmaf(-2.0f*qz, p[3*i+2], d);
            uint32 u = __float_as_uint(d);
            kj[j] = (u & 0x80000000u) ? ~u : (u | 0x80000000u);
        }

        uint32 prefix = 0, kth = KNN;
        for (int pass = 0; pass < 8; ++pass) {
            const int sh = 28 - 4*pass;
            if (tid < 16*17) hist[tid] = 0;
            __syncthreads();
            if (pass == 0) {
#pragma unroll
                for (int j = 0; j < 32; ++j)
                    atomicAdd(&hist[wid*17 + (kj[j] >> 28)], 1u);
            } else {
                const int shp = sh + 4;
#pragma unroll
                for (int j = 0; j < 32; ++j)
                    if ((kj[j] >> shp) == prefix)
                        atomicAdd(&hist[wid*17 + ((kj[j] >> sh) & 15u)], 1u);
            }
            __syncthreads();
            if (wid == 0) {
                uint32 c = 0;
                if (lane < 16) {
#pragma unroll
                    for (int w = 0; w < 16; ++w) c += hist[w*17 + lane];
                }
                uint32 inc = c;
#pragma unroll
                for (int off = 1; off < 16; off <<= 1) {
                    uint32 o = __shfl_up(inc, off);
                    if (lane >= off) inc += o;
                }
                const uint32 exc = inc - c;
                if (lane < 16 && exc < kth && kth <= inc) {   // unique winner lane
                    s_sel[0] = (prefix << 4) | (uint32)lane;
                    s_sel[1] = kth - exc;
                }
            }
            __syncthreads();
            prefix = s_sel[0]; kth = s_sel[1];
        }
        const uint32 keyT = prefix;     // exact key of the 16th smallest

        if (tid == 0) s_cnt = 0;
        __syncthreads();
#pragma unroll
        for (int j = 0; j < 32; ++j) {
            if (kj[j] <= keyT) {
                int ps = atomicAdd(&s_cnt, 1);
                if (ps < 1024) {
                    const int i = tid + (j << 10);
                    list[ps] = ((uint64)kj[j] << 32) | (uint32)i;
                }
            }
        }
        __syncthreads();
        if (wid == 0) {
            const int n = (s_cnt < 1024) ? s_cnt : 1024;
            uint64 lastv = 0ull;
            for (int r = 0; r < KNN; ++r) {
                uint64 mk = ~0ull;
                for (int e = lane; e < n; e += 64) {
                    uint64 v = list[e];
                    if (v > lastv && v < mk) mk = v;
                }
#pragma unroll
                for (int off = 32; off > 0; off >>= 1) {
                    uint64 o = __shfl_xor(mk, off);
                    if (o < mk) mk = o;
                }
                if (lane == 0) knn[b*KNN + r] = (int)(mk & 0xFFFFFFFFull);
                lastv = mk;
            }
        }
        __syncthreads();   // protect hist/s_cnt/list reuse across grid-stride iters
    }
}

// ---- unique-slot stats: weighted per-channel sum/sumsq of h over nuniq slots ----
__global__ void __launch_bounds__(128) ustats_kernel(const float* __restrict__ p,
                                                     const float* __restrict__ x,
                                                     const float* __restrict__ W,
                                                     const int* __restrict__ knn,
                                                     const int* __restrict__ meta,
                                                     float* __restrict__ part) {
    __shared__ float g[GDIM];
    const int t = threadIdx.x;
    const int nun = meta[0], cs = meta[1], cl = meta[2];
    float s_sum = 0.f, s_sq = 0.f;
    for (int s = blockIdx.x; s < nun; s += SBLK) {
        float ls = 0.f, lq = 0.f;
        for (int k = 0; k < KNN; ++k) {
            const int pt = knn[s*KNN + k];
            if (t < 3)         g[t] = p[3*pt + t];
            else if (t < GDIM) g[t] = x[(pt << 6) + t - 3];
            __syncthreads();
            float acc = 0.f;
#pragma unroll
            for (int c = 0; c < GDIM; ++c) acc = fmaf(g[c], W[c*C_OUT + t], acc);
            ls += acc;
            lq = fmaf(acc, acc, lq);
            __syncthreads();
        }
        const float cf = (float)slot_count(s, nun, cs, cl, M_PTS);
        s_sum = fmaf(cf, ls, s_sum);
        s_sq  = fmaf(cf, lq, s_sq);
    }
    part[blockIdx.x*256 + t]       = s_sum;
    part[blockIdx.x*256 + 128 + t] = s_sq;
}

// ---------------- finalize BN: scale/shift per channel ----------------
__global__ void __launch_bounds__(128) bnfin_kernel(const float* __restrict__ part,
                                                    const float* __restrict__ gamma,
                                                    const float* __restrict__ beta,
                                                    float* __restrict__ scale,
                                                    float* __restrict__ shift) {
    const int t = threadIdx.x;
    float s = 0.f, q = 0.f;
    for (int b = 0; b < SBLK; ++b) {
        s += part[b*256 + t];
        q += part[b*256 + 128 + t];
    }
    const float inv = 1.0f / (float)(M_PTS * KNN);
    const float mean = s * inv;
    const float var  = q * inv - mean*mean;
    const float sc   = gamma[t] * rsqrtf(var + BN_EPS);
    scale[t] = sc;
    shift[t] = fmaf(-mean, sc, beta[t]);
}

// ---- unique-slot output rows: slot(m)==m for m<nuniq, write directly to xout ----
__global__ void __launch_bounds__(128) uout_kernel(const float* __restrict__ p,
                                                   const float* __restrict__ x,
                                                   const float* __restrict__ W,
                                                   const int* __restrict__ knn,
                                                   const int* __restrict__ meta,
                                                   const float* __restrict__ scale,
                                                   const float* __restrict__ shift,
                                                   float* __restrict__ xout) {
    __shared__ float g[GDIM];
    const int t = threadIdx.x;
    const int nun = meta[0];
    const float sc = scale[t], sh = shift[t];
    for (int s = blockIdx.x; s < nun; s += SBLK) {
        float mx = 0.f;   // max_k relu(y_k) == max(0, max_k y_k)
        for (int k = 0; k < KNN; ++k) {
            const int pt = knn[s*KNN + k];
            if (t < 3)         g[t] = p[3*pt + t];
            else if (t < GDIM) g[t] = x[(pt << 6) + t - 3];
            __syncthreads();
            float acc = 0.f;
#pragma unroll
            for (int c = 0; c < GDIM; ++c) acc = fmaf(g[c], W[c*C_OUT + t], acc);
            mx = fmaxf(mx, fmaf(acc, sc, sh));
            __syncthreads();
        }
        xout[s*C_OUT + t] = mx;
    }
}

// ---- broadcast periodic rows: xout[m] = xout[slot(m)] for m >= nuniq (float4) ----
__global__ void __launch_bounds__(256) bcast_kernel(const int* __restrict__ meta,
                                                    float* __restrict__ xout) {
    const int nun = meta[0], cs = meta[1], cl = meta[2];
    const int idx = blockIdx.x * 256 + threadIdx.x;      // float4 index
    const int m = nun + (idx >> 5);                      // 32 float4 per row
    if (m >= M_PTS) return;
    const int c4 = idx & 31;
    const int sl = cs + (m - cs) % cl;
    float4 v = ((const float4*)xout)[sl*32 + c4];
    ((float4*)xout)[(size_t)m*32 + c4] = v;
}

extern "C" void kernel_launch(void* const* d_in, const int* in_sizes, int n_in,
                              void* d_out, int out_size, void* d_ws, size_t ws_size,
                              hipStream_t stream) {
    (void)in_sizes; (void)n_in; (void)out_size; (void)ws_size;
    const float* p     = (const float*)d_in[0];
    const float* x     = (const float*)d_in[1];
    // d_in[2] = o (unused)
    const float* W     = (const float*)d_in[3];
    const float* gamma = (const float*)d_in[4];
    const float* beta  = (const float*)d_in[5];

    float* out  = (float*)d_out;
    float* newp = out;               // [M_PTS, 3]
    float* xout = out + M_PTS * 3;   // [M_PTS, C_OUT]

    char* ws = (char*)d_ws;
    int*   fps   = (int*)  (ws + OFF_FPS);
    int*   pos   = (int*)  (ws + OFF_POS);
    int*   meta  = (int*)  (ws + OFF_META);
    float* pp    = (float*)(ws + OFF_PP);
    int*   knn   = (int*)  (ws + OFF_KNN);
    float* part  = (float*)(ws + OFF_PART);
    float* scale = (float*)(ws + OFF_SCALE);
    float* shift = (float*)(ws + OFF_SHIFT);

    pp_kernel    <<<(N_PTS + 255)/256, 256, 0, stream>>>(p, pp);
    fps_kernel   <<<1, 1024, 0, stream>>>(p, fps, pos, meta, newp);
    knn_kernel   <<<16, 1024, 0, stream>>>(p, pp, fps, meta, knn);
    ustats_kernel<<<SBLK, 128, 0, stream>>>(p, x, W, knn, meta, part);
    bnfin_kernel <<<1, 128, 0, stream>>>(part, gamma, beta, scale, shift);
    uout_kernel  <<<SBLK, 128, 0, stream>>>(p, x, W, knn, meta, scale, shift, xout);
    bcast_kernel <<<M_PTS*32/256, 256, 0, stream>>>(meta, xout);
}

// Round 5
// 116.473 us; speedup vs baseline: 11.4783x; 1.1883x over previous
//
#include <hip/hip_runtime.h>

#define N_PTS 32768
#define M_PTS 8192      // N / STRIDE
#define C_IN  64
#define C_OUT 128
#define KNN   16
#define GDIM  67        // 3 + C_IN
#define BN_EPS 1e-5f
#define SBLK  64        // blocks for ustats/uout grid-stride

// workspace offsets (bytes)
#define OFF_FPS   0u          // int[M_PTS]
#define OFF_POS   32768u      // int[N_PTS]
#define OFF_META  163840u     // int[8]: [0]=nuniq [1]=cycStart [2]=cycLen
#define OFF_PP    163904u     // float[N_PTS]
#define OFF_KNN   294976u     // int[M_PTS*KNN] (only first nuniq*KNN used)
#define OFF_PART  819264u     // float[SBLK*256]
#define OFF_SCALE 884800u     // float[C_OUT]
#define OFF_SHIFT 885312u     // float[C_OUT]

typedef unsigned int uint32;
typedef unsigned long long uint64;

// multiplicity of unique slot s in the length-M periodic index sequence
__device__ __forceinline__ int slot_count(int s, int nun, int cs, int cl, int M) {
    if (s < cs) return 1;                 // pre-cycle slot: occurs once
    const int E = M - nun;                // extended (periodic) occurrences
    const int base = E / cl, rem = E % cl;
    const int start = (nun - cs) % cl;    // residue of first extended index
    int off = (s - cs) - start; if (off < 0) off += cl;
    return 1 + base + (off < rem ? 1 : 0);
}

// ---------------- pp = ||p||^2 ----------------
__global__ void pp_kernel(const float* __restrict__ p, float* __restrict__ pp) {
    int i = blockIdx.x * blockDim.x + threadIdx.x;
    if (i < N_PTS) {
        float px = p[3*i], py = p[3*i+1], pz = p[3*i+2];
        pp[i] = px*px + py*py + pz*pz;
    }
}

// ---------------- FPS chain (argmax to LAST point), cycle-detected ----------------
__global__ void __launch_bounds__(1024) fps_kernel(const float* __restrict__ p,
                                                   int* __restrict__ fps,
                                                   int* __restrict__ pos,
                                                   int* __restrict__ meta,
                                                   float* __restrict__ newp) {
    __shared__ float wv_d[16];
    __shared__ int   wv_i[16];
    __shared__ int s_last, s_done, s_cs;
    const int tid  = threadIdx.x;
    const int lane = tid & 63;
    const int wid  = tid >> 6;

    for (int i = tid; i < N_PTS; i += 1024) pos[i] = -1;
    if (tid == 0) { fps[0] = 0; pos[0] = 0; s_last = 0; s_done = 0; s_cs = 0; }
    __syncthreads();

    int t = 1;
    while (t < M_PTS) {
        const int last = s_last;
        const float qx = p[3*last], qy = p[3*last+1], qz = p[3*last+2];
        float bd = -1.0f; int bi = 0;
        for (int i = tid; i < N_PTS; i += 1024) {
            // match numpy: ((dx^2 + dy^2) + dz^2), no FMA contraction
            float dx = __fsub_rn(p[3*i],   qx);
            float dy = __fsub_rn(p[3*i+1], qy);
            float dz = __fsub_rn(p[3*i+2], qz);
            float d  = __fadd_rn(__fadd_rn(__fmul_rn(dx,dx), __fmul_rn(dy,dy)),
                                 __fmul_rn(dz,dz));
            if (d > bd) { bd = d; bi = i; }   // strict > keeps first (smallest i) per thread
        }
        // wave-level lex-max (d, then smaller idx)
#pragma unroll
        for (int off = 32; off > 0; off >>= 1) {
            float od = __shfl_xor(bd, off);
            int   oi = __shfl_xor(bi, off);
            if (od > bd || (od == bd && oi < bi)) { bd = od; bi = oi; }
        }
        if (lane == 0) { wv_d[wid] = bd; wv_i[wid] = bi; }
        __syncthreads();
        if (wid == 0) {
            float rd = (lane < 16) ? wv_d[lane] : -1.0f;
            int   ri = (lane < 16) ? wv_i[lane] : 0x7fffffff;
#pragma unroll
            for (int off = 8; off > 0; off >>= 1) {
                float od = __shfl_xor(rd, off);
                int   oi = __shfl_xor(ri, off);
                if (od > rd || (od == rd && oi < ri)) { rd = od; ri = oi; }
            }
            if (lane == 0) {
                int nxt = ri;
                if (pos[nxt] >= 0) { s_cs = pos[nxt]; s_done = 1; }
                else { pos[nxt] = t; fps[t] = nxt; s_last = nxt; }
            }
        }
        __syncthreads();
        if (s_done) break;
        ++t;
    }

    if (tid == 0) {
        if (s_done) { meta[0] = t; meta[1] = s_cs; meta[2] = t - s_cs; }
        else        { meta[0] = M_PTS; meta[1] = 0; meta[2] = 1; }
    }
    __syncthreads();
    if (s_done) {
        const int s = s_cs, L = t - s_cs;
        for (int u = t + tid; u < M_PTS; u += 1024)
            fps[u] = fps[s + (u - s) % L];
    }
    __syncthreads();
    for (int e = tid; e < M_PTS; e += 1024) {
        int id = fps[e];
        newp[3*e]   = p[3*id];
        newp[3*e+1] = p[3*id+1];
        newp[3*e+2] = p[3*id+2];
    }
}

// ---------------- exact kNN: 16 rounds of block-wide lex-min extraction ----------
// Keys in registers (kj[32], static indices). Per round: per-thread min-of-32,
// pack (key,idx) u64, wave shfl-min, 16-wave LDS tournament, winner consumes
// its slot via unrolled static-index cndmask sweep. No atomics, no LDS lists.
__global__ void __launch_bounds__(1024, 4) knn_kernel(const float* __restrict__ p,
                                                      const float* __restrict__ pp,
                                                      const int* __restrict__ fps,
                                                      const int* __restrict__ meta,
                                                      int* __restrict__ knn) {
    const int tid  = threadIdx.x;
    const int lane = tid & 63;
    const int wid  = tid >> 6;          // 16 waves
    const int nun  = meta[0];

    __shared__ uint64 wv_p[16];
    __shared__ uint64 s_win;

    for (int b = blockIdx.x; b < nun; b += gridDim.x) {
        const int cpt = fps[b];
        const float qx = p[3*cpt], qy = p[3*cpt+1], qz = p[3*cpt+2];

        uint32 kj[32];
#pragma unroll
        for (int j = 0; j < 32; ++j) {
            const int i = tid + (j << 10);
            float d = fmaf(-2.0f*qx, p[3*i],   pp[i]);
            d       = fmaf(-2.0f*qy, p[3*i+1], d);
            d       = fmaf(-2.0f*qz, p[3*i+2], d);
            uint32 u = __float_as_uint(d);
            kj[j] = (u & 0x80000000u) ? ~u : (u | 0x80000000u);
        }

        for (int r = 0; r < KNN; ++r) {
            // per-thread lex-min over (key, idx): ascending j scan, strict <
            uint32 mk = kj[0]; int mj = 0;
#pragma unroll
            for (int j = 1; j < 32; ++j)
                if (kj[j] < mk) { mk = kj[j]; mj = j; }
            uint64 pk = ((uint64)mk << 32) | (uint32)(tid + (mj << 10));

            // wave min
#pragma unroll
            for (int off = 32; off > 0; off >>= 1) {
                uint64 o = __shfl_xor(pk, off);
                if (o < pk) pk = o;
            }
            if (lane == 0) wv_p[wid] = pk;
            __syncthreads();
            if (wid == 0) {
                uint64 rp = (lane < 16) ? wv_p[lane] : ~0ull;
#pragma unroll
                for (int off = 8; off > 0; off >>= 1) {
                    uint64 o = __shfl_xor(rp, off);
                    if (o < rp) rp = o;
                }
                if (lane == 0) s_win = rp;
            }
            __syncthreads();
            const uint64 win = s_win;
            const int win_idx = (int)(win & 0xFFFFFFFFull);
            if (tid == 0) knn[b*KNN + r] = win_idx;
            // consume: winner thread blanks its slot (static indices only)
            if (tid == (win_idx & 1023)) {
                const int jw = win_idx >> 10;
#pragma unroll
                for (int j = 0; j < 32; ++j)
                    if (j == jw) kj[j] = 0xFFFFFFFFu;
            }
            __syncthreads();
        }
    }
}

// ---- unique-slot stats: weighted per-channel sum/sumsq of h over nuniq slots ----
__global__ void __launch_bounds__(128) ustats_kernel(const float* __restrict__ p,
                                                     const float* __restrict__ x,
                                                     const float* __restrict__ W,
                                                     const int* __restrict__ knn,
                                                     const int* __restrict__ meta,
                                                     float* __restrict__ part) {
    __shared__ float g[GDIM];
    const int t = threadIdx.x;
    const int nun = meta[0], cs = meta[1], cl = meta[2];
    float s_sum = 0.f, s_sq = 0.f;
    for (int s = blockIdx.x; s < nun; s += SBLK) {
        float ls = 0.f, lq = 0.f;
        for (int k = 0; k < KNN; ++k) {
            const int pt = knn[s*KNN + k];
            if (t < 3)         g[t] = p[3*pt + t];
            else if (t < GDIM) g[t] = x[(pt << 6) + t - 3];
            __syncthreads();
            float acc = 0.f;
#pragma unroll
            for (int c = 0; c < GDIM; ++c) acc = fmaf(g[c], W[c*C_OUT + t], acc);
            ls += acc;
            lq = fmaf(acc, acc, lq);
            __syncthreads();
        }
        const float cf = (float)slot_count(s, nun, cs, cl, M_PTS);
        s_sum = fmaf(cf, ls, s_sum);
        s_sq  = fmaf(cf, lq, s_sq);
    }
    part[blockIdx.x*256 + t]       = s_sum;
    part[blockIdx.x*256 + 128 + t] = s_sq;
}

// ---------------- finalize BN: scale/shift per channel ----------------
__global__ void __launch_bounds__(128) bnfin_kernel(const float* __restrict__ part,
                                                    const float* __restrict__ gamma,
                                                    const float* __restrict__ beta,
                                                    float* __restrict__ scale,
                                                    float* __restrict__ shift) {
    const int t = threadIdx.x;
    float s = 0.f, q = 0.f;
    for (int b = 0; b < SBLK; ++b) {
        s += part[b*256 + t];
        q += part[b*256 + 128 + t];
    }
    const float inv = 1.0f / (float)(M_PTS * KNN);
    const float mean = s * inv;
    const float var  = q * inv - mean*mean;
    const float sc   = gamma[t] * rsqrtf(var + BN_EPS);
    scale[t] = sc;
    shift[t] = fmaf(-mean, sc, beta[t]);
}

// ---- unique-slot output rows: slot(m)==m for m<nuniq, write directly to xout ----
__global__ void __launch_bounds__(128) uout_kernel(const float* __restrict__ p,
                                                   const float* __restrict__ x,
                                                   const float* __restrict__ W,
                                                   const int* __restrict__ knn,
                                                   const int* __restrict__ meta,
                                                   const float* __restrict__ scale,
                                                   const float* __restrict__ shift,
                                                   float* __restrict__ xout) {
    __shared__ float g[GDIM];
    const int t = threadIdx.x;
    const int nun = meta[0];
    const float sc = scale[t], sh = shift[t];
    for (int s = blockIdx.x; s < nun; s += SBLK) {
        float mx = 0.f;   // max_k relu(y_k) == max(0, max_k y_k)
        for (int k = 0; k < KNN; ++k) {
            const int pt = knn[s*KNN + k];
            if (t < 3)         g[t] = p[3*pt + t];
            else if (t < GDIM) g[t] = x[(pt << 6) + t - 3];
            __syncthreads();
            float acc = 0.f;
#pragma unroll
            for (int c = 0; c < GDIM; ++c) acc = fmaf(g[c], W[c*C_OUT + t], acc);
            mx = fmaxf(mx, fmaf(acc, sc, sh));
            __syncthreads();
        }
        xout[s*C_OUT + t] = mx;
    }
}

// ---- broadcast periodic rows: xout[m] = xout[slot(m)] for m >= nuniq (float4) ----
__global__ void __launch_bounds__(256) bcast_kernel(const int* __restrict__ meta,
                                                    float* __restrict__ xout) {
    const int nun = meta[0], cs = meta[1], cl = meta[2];
    const int idx = blockIdx.x * 256 + threadIdx.x;      // float4 index
    const int m = nun + (idx >> 5);                      // 32 float4 per row
    if (m >= M_PTS) return;
    const int c4 = idx & 31;
    const int sl = cs + (m - cs) % cl;
    float4 v = ((const float4*)xout)[sl*32 + c4];
    ((float4*)xout)[(size_t)m*32 + c4] = v;
}

extern "C" void kernel_launch(void* const* d_in, const int* in_sizes, int n_in,
                              void* d_out, int out_size, void* d_ws, size_t ws_size,
                              hipStream_t stream) {
    (void)in_sizes; (void)n_in; (void)out_size; (void)ws_size;
    const float* p     = (const float*)d_in[0];
    const float* x     = (const float*)d_in[1];
    // d_in[2] = o (unused)
    const float* W     = (const float*)d_in[3];
    const float* gamma = (const float*)d_in[4];
    const float* beta  = (const float*)d_in[5];

    float* out  = (float*)d_out;
    float* newp = out;               // [M_PTS, 3]
    float* xout = out + M_PTS * 3;   // [M_PTS, C_OUT]

    char* ws = (char*)d_ws;
    int*   fps   = (int*)  (ws + OFF_FPS);
    int*   pos   = (int*)  (ws + OFF_POS);
    int*   meta  = (int*)  (ws + OFF_META);
    float* pp    = (float*)(ws + OFF_PP);
    int*   knn   = (int*)  (ws + OFF_KNN);
    float* part  = (float*)(ws + OFF_PART);
    float* scale = (float*)(ws + OFF_SCALE);
    float* shift = (float*)(ws + OFF_SHIFT);

    pp_kernel    <<<(N_PTS + 255)/256, 256, 0, stream>>>(p, pp);
    fps_kernel   <<<1, 1024, 0, stream>>>(p, fps, pos, meta, newp);
    knn_kernel   <<<16, 1024, 0, stream>>>(p, pp, fps, meta, knn);
    ustats_kernel<<<SBLK, 128, 0, stream>>>(p, x, W, knn, meta, part);
    bnfin_kernel <<<1, 128, 0, stream>>>(part, gamma, beta, scale, shift);
    uout_kernel  <<<SBLK, 128, 0, stream>>>(p, x, W, knn, meta, scale, shift, xout);
    bcast_kernel <<<M_PTS*32/256, 256, 0, stream>>>(meta, xout);
}